// Round 1
// baseline (1020.675 us; speedup 1.0000x reference)
//
#include <hip/hip_runtime.h>
#include <math.h>

#define N_ROWS 4096
#define V_DIM  50257
#define THREADS 256

// Combine two online-logsumexp states (m,s) <- (m,s) ⊕ (mo,so)
__device__ __forceinline__ void lse_combine(float& m, float& s, float mo, float so) {
    float mn = fmaxf(m, mo);
    s = s * __expf(m - mn) + so * __expf(mo - mn);
    m = mn;
}

__global__ __launch_bounds__(THREADS) void
ls_row_kernel(const float* __restrict__ logits,
              const int* __restrict__ labels,
              float* __restrict__ partial,
              float smooth, float cms /* conf - smooth */) {
    const int row = blockIdx.x;
    const int tid = threadIdx.x;
    const float* __restrict__ p = logits + (size_t)row * V_DIM;

    // Label logit: one scalar load by thread 0, issued early.
    float x_lbl = 0.0f;
    if (tid == 0) x_lbl = p[labels[row]];

    // Row base alignment: row*V mod 4 == row mod 4 (V ≡ 1 mod 4).
    // Skip `pre` scalars so the float4 region is 16B-aligned.
    const int pre   = (4 - (row & 3)) & 3;
    const int main4 = (V_DIM - pre) >> 2;          // # of float4 groups
    const int tail_start = pre + (main4 << 2);
    const int n_extra = pre + (V_DIM - tail_start); // <= 6 scalars total

    float m = -INFINITY;  // running max
    float s = 0.0f;       // running sum of exp(x - m)
    float t = 0.0f;       // running plain sum

    const float4* __restrict__ p4 = reinterpret_cast<const float4*>(p + pre);
    for (int j = tid; j < main4; j += THREADS) {
        float4 x = p4[j];
        t += (x.x + x.y) + (x.z + x.w);
        float m4 = fmaxf(fmaxf(x.x, x.y), fmaxf(x.z, x.w));
        float mn = fmaxf(m, m4);
        s = s * __expf(m - mn)
          + ((__expf(x.x - mn) + __expf(x.y - mn))
          +  (__expf(x.z - mn) + __expf(x.w - mn)));
        m = mn;
    }
    // Prologue + tail scalars (at most 6 across the whole block).
    for (int j = tid; j < n_extra; j += THREADS) {
        int idx = (j < pre) ? j : tail_start + (j - pre);
        float x = p[idx];
        t += x;
        float mn = fmaxf(m, x);
        s = s * __expf(m - mn) + __expf(x - mn);
        m = mn;
    }

    // Wave64 butterfly reduce (every lane processed >= 49 elements, m finite).
    for (int off = 32; off > 0; off >>= 1) {
        float mo = __shfl_down(m, off, 64);
        float so = __shfl_down(s, off, 64);
        float to = __shfl_down(t, off, 64);
        lse_combine(m, s, mo, so);
        t += to;
    }

    __shared__ float sm[4], ss[4], st[4];
    const int wave = tid >> 6;
    if ((tid & 63) == 0) { sm[wave] = m; ss[wave] = s; st[wave] = t; }
    __syncthreads();

    if (tid == 0) {
        float M = sm[0], S = ss[0], T = st[0];
        for (int w = 1; w < 4; ++w) {
            lse_combine(M, S, sm[w], ss[w]);
            T += st[w];
        }
        float lse = M + __logf(S);
        partial[row] = smooth * ((float)V_DIM * lse - T) + cms * (lse - x_lbl);
    }
}

__global__ __launch_bounds__(THREADS) void
ls_reduce_kernel(const float* __restrict__ partial, float* __restrict__ out, float C) {
    const int tid = threadIdx.x;
    float acc = 0.0f;
    for (int i = tid; i < N_ROWS; i += THREADS) acc += partial[i];
    for (int off = 32; off > 0; off >>= 1) acc += __shfl_down(acc, off, 64);
    __shared__ float sacc[4];
    if ((tid & 63) == 0) sacc[tid >> 6] = acc;
    __syncthreads();
    if (tid == 0) out[0] = (sacc[0] + sacc[1]) + (sacc[2] + sacc[3]) + C;
}

extern "C" void kernel_launch(void* const* d_in, const int* in_sizes, int n_in,
                              void* d_out, int out_size, void* d_ws, size_t ws_size,
                              hipStream_t stream) {
    const float* logits = (const float*)d_in[0];
    const int*   labels = (const int*)d_in[1];
    float* partial = (float*)d_ws;   // 4096 floats = 16 KB, overwritten every call
    float* out     = (float*)d_out;

    // Constants, matching jnp.float32 semantics (threshold is ~2% so double
    // intermediates here are more than fine).
    const double smooth_d = 0.1 / (double)(V_DIM - 1);
    const float  smooth   = (float)smooth_d;
    const float  conf     = 1.0f - 0.1f;
    const float  log_smooth = logf(smooth);
    const float  log_conf   = logf(conf);
    const float  cms = conf - smooth;
    // C = N*smooth*log_smooth*(V-1) + N*conf*log_conf
    const float C = (float)((double)N_ROWS * (double)smooth * (double)log_smooth * (double)(V_DIM - 1)
                          + (double)N_ROWS * (double)conf * (double)log_conf);

    ls_row_kernel<<<N_ROWS, THREADS, 0, stream>>>(logits, labels, partial, smooth, cms);
    ls_reduce_kernel<<<1, THREADS, 0, stream>>>(partial, out, C);
}